// Round 8
// baseline (75.060 us; speedup 1.0000x reference)
//
#include <hip/hip_runtime.h>
#include <math.h>

#define DD 8
#define MM 7
#define MOO 9
#define NPTS 100
#define EPSF 1e-5f

#define THREADS 1024
#define ITERS 8           // uint4 loads per thread; THREADS*4*ITERS == 32768
#define CAP 256           // candidate buffer capacity per row
#define NBUCK 4096        // hi-12-bit buckets

// ---------------- pack: antecedents -> packed byte-offset word --------------
// lo 16 bits: byte offset into float2 quad table 0   = (code & 4095) * 8
// hi 16 bits: byte offset into float2 quad table 1   = (code >> 12) * 8 + 32768
//             (table-1 base PRE-ADDED -> no VALU add per rule in main kernel)
// bucket id (for sort) = (w >> 19) & 4095 == code >> 12.
__global__ __launch_bounds__(256) void pack_kernel(const int* __restrict__ ant,
                                                   unsigned* __restrict__ g_off,
                                                   int R) {
    int r = blockIdx.x * 256 + threadIdx.x;
    if (r < R) {
        const int4* a = reinterpret_cast<const int4*>(ant) + (size_t)r * 2;
        int4 lo = a[0], hi = a[1];
        int v[8] = {lo.x, lo.y, lo.z, lo.w, hi.x, hi.y, hi.z, hi.w};
        unsigned code = 0u;
        #pragma unroll
        for (int i = 0; i < 8; ++i) {
            int c = v[i];
            c = (c < 0) ? 7 : (c > MM - 1 ? MM - 1 : c);   // -1 -> wildcard slot 7
            code |= (unsigned)c << (3 * i);
        }
        g_off[r] = ((code & 4095u) << 3) | ((((code >> 12) << 3) + 32768u) << 16);
    }
}

// ---------------- hist+scan: one block -> exclusive bucket bases ------------
// Rebuilds the histogram from g_off each call (no memset, no stale state).
__global__ __launch_bounds__(1024) void hist_scan_kernel(const unsigned* __restrict__ g_off,
                                                         unsigned* __restrict__ g_base,
                                                         int R) {
    __shared__ unsigned hist[NBUCK];
    __shared__ unsigned aux[1024];
    const int tid = threadIdx.x;

    for (int i = tid; i < NBUCK; i += 1024) hist[i] = 0u;
    __syncthreads();

    for (int r = tid; r < R; r += 1024)
        atomicAdd(&hist[(g_off[r] >> 19) & 4095u], 1u);
    __syncthreads();

    unsigned h0 = hist[4 * tid],     h1 = hist[4 * tid + 1];
    unsigned h2 = hist[4 * tid + 2], h3 = hist[4 * tid + 3];
    aux[tid] = h0 + h1 + h2 + h3;
    __syncthreads();
    for (int off = 1; off < 1024; off <<= 1) {
        unsigned v = (tid >= off) ? aux[tid - off] : 0u;
        __syncthreads();
        aux[tid] += v;
        __syncthreads();
    }
    unsigned base = tid ? aux[tid - 1] : 0u;
    g_base[4 * tid]     = base;
    g_base[4 * tid + 1] = base + h0;
    g_base[4 * tid + 2] = base + h0 + h1;
    g_base[4 * tid + 3] = base + h0 + h1 + h2;
}

// ---------------- scatter: parallel bucket placement + wave permutation -----
// Rank q lands at p so each main-kernel wave-instruction reads 64 CONSECUTIVE
// sorted rules (hi-table -> ~8-word broadcast runs). Atomic order within a
// bucket is arbitrary -- harmless (final selection uses original index).
__global__ __launch_bounds__(256) void scatter_kernel(const unsigned* __restrict__ g_off,
                                                      unsigned* __restrict__ g_base,
                                                      unsigned* __restrict__ g_soff,
                                                      int* __restrict__ g_sidx,
                                                      int R) {
    int r = blockIdx.x * 256 + threadIdx.x;
    if (r < R) {
        unsigned w = g_off[r];
        unsigned q = atomicAdd(&g_base[(w >> 19) & 4095u], 1u);
        unsigned p = (q & ~255u) | ((q & 63u) << 2) | ((q >> 6) & 3u);
        g_soff[p] = w;
        g_sidx[p] = r;
    }
}

// ---------------- main kernel: 1024 threads per PAIR of batch rows ----------
// float2 tables {row0,row1}: one ds_read_b64 serves both rows. Phase 3 loads
// ALL 8 uint4 code words up-front (32 VGPR) -- one vmcnt ramp, then the gather
// loop is pure LDS+VALU with no mid-loop VMEM stalls (R7 showed the in-phase
// per-iter L2 wait left both pipes ~60% idle).
__global__ __launch_bounds__(THREADS, 8) void anfis2(
    const float* __restrict__ x,
    const unsigned* __restrict__ stream_off,
    const int* __restrict__ g_sidx,
    const int* __restrict__ consequents,
    const float* __restrict__ in_centers,   // [D][M]
    const float* __restrict__ in_widths,    // [D][M]
    const float* __restrict__ out_centers,  // [MO]
    const float* __restrict__ out_widths,   // [MO]
    float* __restrict__ out)
{
    __shared__ float2  quads2[8192];     // 2 tables x 4096, {row0,row1}
    __shared__ float   mu[2][64];        // [row][d*8+c], c==7 -> 1.0
    __shared__ float   pairs[2][256];    // [row][4 tables x 64]
    __shared__ float   s0s[MOO], s1s[MOO];
    __shared__ float2  smax2[THREADS];
    __shared__ float   sthr[2];
    __shared__ int     scnt[2];
    __shared__ float   cvals[2][CAP];
    __shared__ int     cidx[2][CAP];
    __shared__ float   wv[2][8];
    __shared__ int     wc[2][8];

    const int tid = threadIdx.x;
    const int b0  = blockIdx.x * 2;

    // --- phase 0: membership tables (both rows) + defuzz constants ---
    if (tid < 128) {
        int row = tid >> 6, d = (tid >> 3) & 7, c = tid & 7;
        float v = 1.0f;
        if (c < MM) {
            float z = (x[(b0 + row) * DD + d] - in_centers[d * MM + c]) / in_widths[d * MM + c];
            v = expf(-0.5f * z * z);
            v = fminf(v, 1.0f);
            v = fmaxf(v, EPSF);
        }
        mu[row][(d << 3) + c] = v;
    } else if (tid < 128 + MOO) {
        int mo = tid - 128;
        float oc = out_centers[mo], ow = out_widths[mo];
        float s0 = 0.0f, s1 = 0.0f;
        for (int p = 0; p < NPTS; ++p) {
            float u = (float)p * (1.0f / 99.0f);
            float z = (u - oc) / ow;
            float e = expf(-0.5f * z * z);
            s0 += e;
            s1 += u * e;
        }
        s0s[mo] = s0;
        s1s[mo] = s1;
    }
    __syncthreads();

    // --- phase 1: pair products, both rows (512 entries total) ---
    if (tid < 512) {
        int row = tid >> 8, e = tid & 255;
        int p = e >> 6, q = e & 63;
        pairs[row][e] = mu[row][(2 * p) * 8 + (q & 7)] * mu[row][(2 * p + 1) * 8 + (q >> 3)];
    }
    if (tid == 0) { scnt[0] = 0; scnt[1] = 0; }
    __syncthreads();

    // --- phase 2: quad product tables as float2 {row0,row1} ---
    #pragma unroll
    for (int k = tid; k < 8192; k += THREADS) {
        int t = k & 4095, h = k >> 12;       // h in {0,1}
        float v0 = pairs[0][h * 128 + (t & 63)] * pairs[0][h * 128 + 64 + ((t >> 6) & 63)];
        float v1 = pairs[1][h * 128 + (t & 63)] * pairs[1][h * 128 + 64 + ((t >> 6) & 63)];
        quads2[k] = make_float2(v0, v1);
    }
    __syncthreads();

    // --- phase 3: all 8 code words preloaded, then pure LDS+VALU gather ---
    const uint4* pk4 = reinterpret_cast<const uint4*>(stream_off);
    const char* qb = (const char*)quads2;
    float mymax0 = -1.0f, mymax1 = -1.0f;
    {
        uint4 k0 = pk4[tid];
        uint4 k1 = pk4[1 * THREADS + tid];
        uint4 k2 = pk4[2 * THREADS + tid];
        uint4 k3 = pk4[3 * THREADS + tid];
        uint4 k4 = pk4[4 * THREADS + tid];
        uint4 k5 = pk4[5 * THREADS + tid];
        uint4 k6 = pk4[6 * THREADS + tid];
        uint4 k7 = pk4[7 * THREADS + tid];

        #define PROC4(KK)                                                        \
        {                                                                        \
            unsigned w_[4] = {(KK).x, (KK).y, (KK).z, (KK).w};                   \
            float2 ra_[4], rt_[4];                                               \
            _Pragma("unroll")                                                    \
            for (int s = 0; s < 4; ++s) {                                        \
                ra_[s] = *(const float2*)(qb + (w_[s] & 0xFFFFu));               \
                rt_[s] = *(const float2*)(qb + (w_[s] >> 16));                   \
            }                                                                    \
            _Pragma("unroll")                                                    \
            for (int s = 0; s < 4; ++s) {                                        \
                mymax0 = fmaxf(mymax0, ra_[s].x * rt_[s].x);                     \
                mymax1 = fmaxf(mymax1, ra_[s].y * rt_[s].y);                     \
            }                                                                    \
        }
        PROC4(k0) PROC4(k1) PROC4(k2) PROC4(k3)
        PROC4(k4) PROC4(k5) PROC4(k6) PROC4(k7)
        #undef PROC4
    }
    smax2[tid] = make_float2(mymax0, mymax1);
    __syncthreads();

    // --- phase 4: waves 0/1 extract 8th-largest thread max per row ---
    if (tid < 128) {
        int row = tid >> 6, lane = tid & 63;
        float m[16];
        #pragma unroll
        for (int k = 0; k < 16; ++k) {
            float2 s = smax2[lane + 64 * k];
            m[k] = row ? s.y : s.x;
        }
        float thr = -1.0f;
        #pragma unroll
        for (int round = 0; round < 8; ++round) {
            float lm = m[0];
            #pragma unroll
            for (int k = 1; k < 16; ++k) lm = fmaxf(lm, m[k]);
            float wm = lm;
            #pragma unroll
            for (int off = 32; off >= 1; off >>= 1)
                wm = fmaxf(wm, __shfl_xor(wm, off, 64));
            unsigned long long bal = __ballot(lm == wm);
            int first = (int)__ffsll(bal) - 1;
            if (lane == first) {                // remove exactly one instance
                bool done = false;
                #pragma unroll
                for (int k = 0; k < 16; ++k) {
                    bool rm = (!done) && (m[k] == wm);
                    m[k] = rm ? -2.0f : m[k];
                    done = done || rm;
                }
            }
            thr = wm;
        }
        if (lane == 0) sthr[row] = thr;
    }
    __syncthreads();

    // --- phase 5: qualifying threads recompute & push candidates per row ---
    {
        const float thr0 = sthr[0], thr1 = sthr[1];
        if (mymax0 >= thr0 || mymax1 >= thr1) {    // ~16-60 threads of 1024
            for (int j = 0; j < ITERS; ++j) {
                uint4 cd = pk4[j * THREADS + tid];
                unsigned cods[4] = {cd.x, cd.y, cd.z, cd.w};
                #pragma unroll
                for (int s = 0; s < 4; ++s) {
                    unsigned w = cods[s];
                    float2 a = *(const float2*)(qb + (w & 0xFFFFu));
                    float2 t = *(const float2*)(qb + (w >> 16));
                    float f0 = a.x * t.x, f1 = a.y * t.y;
                    if (f0 >= thr0) {
                        int flat = (j * THREADS + tid) * 4 + s;
                        int pos = atomicAdd(&scnt[0], 1);
                        if (pos < CAP) { cvals[0][pos] = f0; cidx[0][pos] = g_sidx[flat]; }
                    }
                    if (f1 >= thr1) {
                        int flat = (j * THREADS + tid) * 4 + s;
                        int pos = atomicAdd(&scnt[1], 1);
                        if (pos < CAP) { cvals[1][pos] = f1; cidx[1][pos] = g_sidx[flat]; }
                    }
                }
            }
        }
    }
    __syncthreads();

    // --- phase 6: exact rank selection per row (val desc, orig idx asc) ---
    if (tid < 128) {
        int row = tid >> 6, lane = tid & 63;
        int n = scnt[row] < CAP ? scnt[row] : CAP;
        for (int c = lane; c < n; c += 64) {
            float v  = cvals[row][c];
            int   id = cidx[row][c];
            int rk = 0;
            for (int mI = 0; mI < n; ++mI) {
                float vm = cvals[row][mI];
                int   im = cidx[row][mI];
                rk += ((vm > v) || (vm == v && im < id)) ? 1 : 0;
            }
            if (rk < 8) {
                wv[row][rk] = v;
                wc[row][rk] = consequents[id];
            }
        }
    }
    __syncthreads();

    // --- phase 7: defuzzify (one thread per row) ---
    if (tid == 0 || tid == 64) {
        int row = tid >> 6;
        float num = 0.0f, den = 0.0f;
        #pragma unroll
        for (int k = 0; k < 8; ++k) {
            num += wv[row][k] * s1s[wc[row][k]];
            den += wv[row][k] * s0s[wc[row][k]];
        }
        out[b0 + row] = num / (den + EPSF);
    }
}

// ---------------- generic fallback (round-1 kernel, inline pack) ------------
__global__ __launch_bounds__(256) void anfis_kernel(
    const float* __restrict__ x,
    const int* __restrict__ ant,
    const int* __restrict__ consequents,
    const float* __restrict__ in_centers,
    const float* __restrict__ in_widths,
    const float* __restrict__ out_centers,
    const float* __restrict__ out_widths,
    float* __restrict__ out,
    int R)
{
    __shared__ float mu[64];
    __shared__ float pairs[256];
    __shared__ float s0s[MOO], s1s[MOO];
    __shared__ float svals[256][9];
    __shared__ int   sidx[256][9];

    const int tid = threadIdx.x;
    const int b   = blockIdx.x;

    if (tid < 64) {
        int d = tid >> 3, c = tid & 7;
        float v = 1.0f;
        if (c < MM) {
            float z = (x[b * DD + d] - in_centers[d * MM + c]) / in_widths[d * MM + c];
            v = expf(-0.5f * z * z);
            v = fminf(v, 1.0f);
            v = fmaxf(v, EPSF);
        }
        mu[tid] = v;
    } else if (tid < 64 + MOO) {
        int mo = tid - 64;
        float oc = out_centers[mo], ow = out_widths[mo];
        float s0 = 0.0f, s1 = 0.0f;
        for (int p = 0; p < NPTS; ++p) {
            float u = (float)p * (1.0f / 99.0f);
            float z = (u - oc) / ow;
            float e = expf(-0.5f * z * z);
            s0 += e;
            s1 += u * e;
        }
        s0s[mo] = s0;
        s1s[mo] = s1;
    }
    __syncthreads();

    {
        int p = tid >> 6, q = tid & 63;
        pairs[tid] = mu[(2 * p) * 8 + (q & 7)] * mu[(2 * p + 1) * 8 + (q >> 3)];
    }
    __syncthreads();

    float vals[8];
    int   idxs[8];
    #pragma unroll
    for (int k = 0; k < 8; ++k) { vals[k] = -1.0f; idxs[k] = 0x7fffffff; }

    for (int r = tid; r < R; r += 256) {
        const int4* a = reinterpret_cast<const int4*>(ant) + (size_t)r * 2;
        int4 lo = a[0], hi = a[1];
        int v[8] = {lo.x, lo.y, lo.z, lo.w, hi.x, hi.y, hi.z, hi.w};
        unsigned code = 0u;
        #pragma unroll
        for (int i = 0; i < 8; ++i) {
            int c = v[i];
            c = (c < 0) ? 7 : (c > MM - 1 ? MM - 1 : c);
            code |= (unsigned)c << (3 * i);
        }
        float f = pairs[code & 63]
                * pairs[64  + ((code >> 6)  & 63)]
                * pairs[128 + ((code >> 12) & 63)]
                * pairs[192 + ((code >> 18) & 63)];
        if (f > vals[7]) {
            float nv = f; int ni = r;
            #pragma unroll
            for (int k = 0; k < 8; ++k) {
                bool take = nv > vals[k];
                float cv = vals[k]; int ci = idxs[k];
                vals[k] = take ? nv : cv;
                idxs[k] = take ? ni : ci;
                nv = take ? cv : nv;
                ni = take ? ci : ni;
            }
        }
    }

    #pragma unroll
    for (int k = 0; k < 8; ++k) { svals[tid][k] = vals[k]; sidx[tid][k] = idxs[k]; }

    for (int off = 128; off >= 1; off >>= 1) {
        __syncthreads();
        if (tid < off) {
            float ov[8]; int oi[8];
            int pa = 0, pb = 0;
            #pragma unroll
            for (int k = 0; k < 8; ++k) {
                float va = svals[tid][pa];        int ia = sidx[tid][pa];
                float vb = svals[tid + off][pb];  int ib = sidx[tid + off][pb];
                bool ta = (va > vb) || ((va == vb) && (ia < ib));
                ov[k] = ta ? va : vb;
                oi[k] = ta ? ia : ib;
                pa += ta ? 1 : 0;
                pb += ta ? 0 : 1;
            }
            #pragma unroll
            for (int k = 0; k < 8; ++k) { svals[tid][k] = ov[k]; sidx[tid][k] = oi[k]; }
        }
    }
    __syncthreads();

    if (tid == 0) {
        float num = 0.0f, den = 0.0f;
        #pragma unroll
        for (int k = 0; k < 8; ++k) {
            float v = svals[0][k];
            int   c = consequents[sidx[0][k]];
            num += v * s1s[c];
            den += v * s0s[c];
        }
        out[b] = num / (den + EPSF);
    }
}

extern "C" void kernel_launch(void* const* d_in, const int* in_sizes, int n_in,
                              void* d_out, int out_size, void* d_ws, size_t ws_size,
                              hipStream_t stream) {
    const float* x      = (const float*)d_in[0];
    const int*   ant    = (const int*)d_in[1];
    const int*   cons   = (const int*)d_in[2];
    const float* in_c   = (const float*)d_in[3];
    const float* in_w   = (const float*)d_in[4];
    const float* out_c  = (const float*)d_in[5];
    const float* out_w  = (const float*)d_in[6];
    float*       out    = (float*)d_out;

    const int B = in_sizes[0] / DD;
    const int R = in_sizes[1] / DD;

    const bool shape_ok = (R == THREADS * 4 * ITERS) && (B % 2 == 0);
    const size_t need = (size_t)R * 12 + (size_t)NBUCK * 4;    // off+soff+sidx+bases

    if (shape_ok && d_ws && ws_size >= need) {
        unsigned* g_off  = (unsigned*)d_ws;
        unsigned* g_soff = g_off + R;
        int*      g_sidx = (int*)(g_soff + R);
        unsigned* g_base = (unsigned*)(g_sidx + R);
        pack_kernel<<<(R + 255) / 256, 256, 0, stream>>>(ant, g_off, R);
        hist_scan_kernel<<<1, 1024, 0, stream>>>(g_off, g_base, R);
        scatter_kernel<<<(R + 255) / 256, 256, 0, stream>>>(g_off, g_base, g_soff, g_sidx, R);
        anfis2<<<B / 2, THREADS, 0, stream>>>(x, g_soff, g_sidx, cons,
                                              in_c, in_w, out_c, out_w, out);
    } else {
        anfis_kernel<<<B, 256, 0, stream>>>(x, ant, cons, in_c, in_w,
                                            out_c, out_w, out, R);
    }
}

// Round 9
// 61.723 us; speedup vs baseline: 1.2161x; 1.2161x over previous
//
#include <hip/hip_runtime.h>
#include <math.h>

#define DD 8
#define MM 7
#define MOO 9
#define NPTS 100
#define EPSF 1e-5f

#define THREADS 1024
#define ITERS 8           // uint4 loads per thread; THREADS*4*ITERS == 32768
#define CAP 256           // candidate buffer capacity per row

// ---------------- pack: antecedents -> packed byte-offset word --------------
// lo 16 bits: byte offset into float2 quad table 0   = (code & 4095) * 8
// hi 16 bits: byte offset into float2 quad table 1   = (code >> 12) * 8 + 32768
// Main kernel converts to float2 indices: lo_idx = (w&0xFFFF)>>3, hi_idx = w>>19
// (hi index includes the +4096 table-1 base).
__global__ __launch_bounds__(256) void pack_kernel(const int* __restrict__ ant,
                                                   unsigned* __restrict__ g_off,
                                                   int R) {
    int r = blockIdx.x * 256 + threadIdx.x;
    if (r < R) {
        const int4* a = reinterpret_cast<const int4*>(ant) + (size_t)r * 2;
        int4 lo = a[0], hi = a[1];
        int v[8] = {lo.x, lo.y, lo.z, lo.w, hi.x, hi.y, hi.z, hi.w};
        unsigned code = 0u;
        #pragma unroll
        for (int i = 0; i < 8; ++i) {
            int c = v[i];
            c = (c < 0) ? 7 : (c > MM - 1 ? MM - 1 : c);   // -1 -> wildcard slot 7
            code |= (unsigned)c << (3 * i);
        }
        g_off[r] = ((code & 4095u) << 3) | ((((code >> 12) << 3) + 32768u) << 16);
    }
}

// ---------------- main kernel: 1024 threads per PAIR of batch rows ----------
// No sort pre-pass (R8 analysis: sort cost ~20us wall vs ~5-9us conflict
// savings). All table accesses are DIRECT __shared__ array indexing so the
// compiler provably emits ds_read_b64 (no generic-pointer/flat-load risk --
// the prime suspect for R6/R7/R8's invariant ~54us).
__global__ __launch_bounds__(THREADS, 8) void anfis2(
    const float* __restrict__ x,
    const unsigned* __restrict__ stream_off,   // packed words, original order
    const int* __restrict__ consequents,
    const float* __restrict__ in_centers,   // [D][M]
    const float* __restrict__ in_widths,    // [D][M]
    const float* __restrict__ out_centers,  // [MO]
    const float* __restrict__ out_widths,   // [MO]
    float* __restrict__ out)
{
    __shared__ float2  quads2[8192];     // 2 tables x 4096, {row0,row1}
    __shared__ float   mu[2][64];        // [row][d*8+c], c==7 -> 1.0
    __shared__ float   pairs[2][256];    // [row][4 tables x 64]
    __shared__ float   s0s[MOO], s1s[MOO];
    __shared__ float2  smax2[THREADS];
    __shared__ float   sthr[2];
    __shared__ int     scnt[2];
    __shared__ float   cvals[2][CAP];
    __shared__ int     cidx[2][CAP];
    __shared__ float   wv[2][8];
    __shared__ int     wc[2][8];

    const int tid = threadIdx.x;
    const int b0  = blockIdx.x * 2;

    // --- phase 0: membership tables (both rows) + defuzz constants ---
    if (tid < 128) {
        int row = tid >> 6, d = (tid >> 3) & 7, c = tid & 7;
        float v = 1.0f;
        if (c < MM) {
            float z = (x[(b0 + row) * DD + d] - in_centers[d * MM + c]) / in_widths[d * MM + c];
            v = expf(-0.5f * z * z);
            v = fminf(v, 1.0f);
            v = fmaxf(v, EPSF);
        }
        mu[row][(d << 3) + c] = v;
    } else if (tid < 128 + MOO) {
        int mo = tid - 128;
        float oc = out_centers[mo], ow = out_widths[mo];
        float s0 = 0.0f, s1 = 0.0f;
        for (int p = 0; p < NPTS; ++p) {
            float u = (float)p * (1.0f / 99.0f);
            float z = (u - oc) / ow;
            float e = expf(-0.5f * z * z);
            s0 += e;
            s1 += u * e;
        }
        s0s[mo] = s0;
        s1s[mo] = s1;
    }
    __syncthreads();

    // --- phase 1: pair products, both rows (512 entries total) ---
    if (tid < 512) {
        int row = tid >> 8, e = tid & 255;
        int p = e >> 6, q = e & 63;
        pairs[row][e] = mu[row][(2 * p) * 8 + (q & 7)] * mu[row][(2 * p + 1) * 8 + (q >> 3)];
    }
    if (tid == 0) { scnt[0] = 0; scnt[1] = 0; }
    __syncthreads();

    // --- phase 2: quad product tables as float2 {row0,row1} ---
    #pragma unroll
    for (int k = tid; k < 8192; k += THREADS) {
        int t = k & 4095, h = k >> 12;       // h in {0,1}
        float v0 = pairs[0][h * 128 + (t & 63)] * pairs[0][h * 128 + 64 + ((t >> 6) & 63)];
        float v1 = pairs[1][h * 128 + (t & 63)] * pairs[1][h * 128 + 64 + ((t >> 6) & 63)];
        quads2[k] = make_float2(v0, v1);
    }
    __syncthreads();

    // --- phase 3: all 8 code words preloaded, pure LDS gather via direct idx ---
    const uint4* pk4 = reinterpret_cast<const uint4*>(stream_off);
    float mymax0 = -1.0f, mymax1 = -1.0f;
    {
        uint4 k0 = pk4[tid];
        uint4 k1 = pk4[1 * THREADS + tid];
        uint4 k2 = pk4[2 * THREADS + tid];
        uint4 k3 = pk4[3 * THREADS + tid];
        uint4 k4 = pk4[4 * THREADS + tid];
        uint4 k5 = pk4[5 * THREADS + tid];
        uint4 k6 = pk4[6 * THREADS + tid];
        uint4 k7 = pk4[7 * THREADS + tid];

        #define PROC4(KK)                                                        \
        {                                                                        \
            unsigned w0_ = (KK).x, w1_ = (KK).y, w2_ = (KK).z, w3_ = (KK).w;     \
            float2 a0_ = quads2[(w0_ & 0xFFFFu) >> 3];                           \
            float2 t0_ = quads2[w0_ >> 19];                                      \
            float2 a1_ = quads2[(w1_ & 0xFFFFu) >> 3];                           \
            float2 t1_ = quads2[w1_ >> 19];                                      \
            float2 a2_ = quads2[(w2_ & 0xFFFFu) >> 3];                           \
            float2 t2_ = quads2[w2_ >> 19];                                      \
            float2 a3_ = quads2[(w3_ & 0xFFFFu) >> 3];                           \
            float2 t3_ = quads2[w3_ >> 19];                                      \
            mymax0 = fmaxf(mymax0, a0_.x * t0_.x);                               \
            mymax1 = fmaxf(mymax1, a0_.y * t0_.y);                               \
            mymax0 = fmaxf(mymax0, a1_.x * t1_.x);                               \
            mymax1 = fmaxf(mymax1, a1_.y * t1_.y);                               \
            mymax0 = fmaxf(mymax0, a2_.x * t2_.x);                               \
            mymax1 = fmaxf(mymax1, a2_.y * t2_.y);                               \
            mymax0 = fmaxf(mymax0, a3_.x * t3_.x);                               \
            mymax1 = fmaxf(mymax1, a3_.y * t3_.y);                               \
        }
        PROC4(k0) PROC4(k1) PROC4(k2) PROC4(k3)
        PROC4(k4) PROC4(k5) PROC4(k6) PROC4(k7)
        #undef PROC4
    }
    smax2[tid] = make_float2(mymax0, mymax1);
    __syncthreads();

    // --- phase 4: waves 0/1 extract 8th-largest thread max per row ---
    if (tid < 128) {
        int row = tid >> 6, lane = tid & 63;
        float m[16];
        #pragma unroll
        for (int k = 0; k < 16; ++k) {
            float2 s = smax2[lane + 64 * k];
            m[k] = row ? s.y : s.x;
        }
        float thr = -1.0f;
        #pragma unroll
        for (int round = 0; round < 8; ++round) {
            float lm = m[0];
            #pragma unroll
            for (int k = 1; k < 16; ++k) lm = fmaxf(lm, m[k]);
            float wm = lm;
            #pragma unroll
            for (int off = 32; off >= 1; off >>= 1)
                wm = fmaxf(wm, __shfl_xor(wm, off, 64));
            unsigned long long bal = __ballot(lm == wm);
            int first = (int)__ffsll(bal) - 1;
            if (lane == first) {                // remove exactly one instance
                bool done = false;
                #pragma unroll
                for (int k = 0; k < 16; ++k) {
                    bool rm = (!done) && (m[k] == wm);
                    m[k] = rm ? -2.0f : m[k];
                    done = done || rm;
                }
            }
            thr = wm;
        }
        if (lane == 0) sthr[row] = thr;
    }
    __syncthreads();

    // --- phase 5: qualifying threads recompute & push candidates per row ---
    // flat position IS the original rule index (no sort) -> exact tie-break.
    {
        const float thr0 = sthr[0], thr1 = sthr[1];
        if (mymax0 >= thr0 || mymax1 >= thr1) {    // ~16-60 threads of 1024
            for (int j = 0; j < ITERS; ++j) {
                uint4 cd = pk4[j * THREADS + tid];
                unsigned cods[4] = {cd.x, cd.y, cd.z, cd.w};
                #pragma unroll
                for (int s = 0; s < 4; ++s) {
                    unsigned w = cods[s];
                    float2 a = quads2[(w & 0xFFFFu) >> 3];
                    float2 t = quads2[w >> 19];
                    float f0 = a.x * t.x, f1 = a.y * t.y;
                    int flat = (j * THREADS + tid) * 4 + s;
                    if (f0 >= thr0) {
                        int pos = atomicAdd(&scnt[0], 1);
                        if (pos < CAP) { cvals[0][pos] = f0; cidx[0][pos] = flat; }
                    }
                    if (f1 >= thr1) {
                        int pos = atomicAdd(&scnt[1], 1);
                        if (pos < CAP) { cvals[1][pos] = f1; cidx[1][pos] = flat; }
                    }
                }
            }
        }
    }
    __syncthreads();

    // --- phase 6: exact rank selection per row (val desc, orig idx asc) ---
    if (tid < 128) {
        int row = tid >> 6, lane = tid & 63;
        int n = scnt[row] < CAP ? scnt[row] : CAP;
        for (int c = lane; c < n; c += 64) {
            float v  = cvals[row][c];
            int   id = cidx[row][c];
            int rk = 0;
            for (int mI = 0; mI < n; ++mI) {
                float vm = cvals[row][mI];
                int   im = cidx[row][mI];
                rk += ((vm > v) || (vm == v && im < id)) ? 1 : 0;
            }
            if (rk < 8) {
                wv[row][rk] = v;
                wc[row][rk] = consequents[id];
            }
        }
    }
    __syncthreads();

    // --- phase 7: defuzzify (one thread per row) ---
    if (tid == 0 || tid == 64) {
        int row = tid >> 6;
        float num = 0.0f, den = 0.0f;
        #pragma unroll
        for (int k = 0; k < 8; ++k) {
            num += wv[row][k] * s1s[wc[row][k]];
            den += wv[row][k] * s0s[wc[row][k]];
        }
        out[b0 + row] = num / (den + EPSF);
    }
}

// ---------------- generic fallback (round-1 kernel, inline pack) ------------
__global__ __launch_bounds__(256) void anfis_kernel(
    const float* __restrict__ x,
    const int* __restrict__ ant,
    const int* __restrict__ consequents,
    const float* __restrict__ in_centers,
    const float* __restrict__ in_widths,
    const float* __restrict__ out_centers,
    const float* __restrict__ out_widths,
    float* __restrict__ out,
    int R)
{
    __shared__ float mu[64];
    __shared__ float pairs[256];
    __shared__ float s0s[MOO], s1s[MOO];
    __shared__ float svals[256][9];
    __shared__ int   sidx[256][9];

    const int tid = threadIdx.x;
    const int b   = blockIdx.x;

    if (tid < 64) {
        int d = tid >> 3, c = tid & 7;
        float v = 1.0f;
        if (c < MM) {
            float z = (x[b * DD + d] - in_centers[d * MM + c]) / in_widths[d * MM + c];
            v = expf(-0.5f * z * z);
            v = fminf(v, 1.0f);
            v = fmaxf(v, EPSF);
        }
        mu[tid] = v;
    } else if (tid < 64 + MOO) {
        int mo = tid - 64;
        float oc = out_centers[mo], ow = out_widths[mo];
        float s0 = 0.0f, s1 = 0.0f;
        for (int p = 0; p < NPTS; ++p) {
            float u = (float)p * (1.0f / 99.0f);
            float z = (u - oc) / ow;
            float e = expf(-0.5f * z * z);
            s0 += e;
            s1 += u * e;
        }
        s0s[mo] = s0;
        s1s[mo] = s1;
    }
    __syncthreads();

    {
        int p = tid >> 6, q = tid & 63;
        pairs[tid] = mu[(2 * p) * 8 + (q & 7)] * mu[(2 * p + 1) * 8 + (q >> 3)];
    }
    __syncthreads();

    float vals[8];
    int   idxs[8];
    #pragma unroll
    for (int k = 0; k < 8; ++k) { vals[k] = -1.0f; idxs[k] = 0x7fffffff; }

    for (int r = tid; r < R; r += 256) {
        const int4* a = reinterpret_cast<const int4*>(ant) + (size_t)r * 2;
        int4 lo = a[0], hi = a[1];
        int v[8] = {lo.x, lo.y, lo.z, lo.w, hi.x, hi.y, hi.z, hi.w};
        unsigned code = 0u;
        #pragma unroll
        for (int i = 0; i < 8; ++i) {
            int c = v[i];
            c = (c < 0) ? 7 : (c > MM - 1 ? MM - 1 : c);
            code |= (unsigned)c << (3 * i);
        }
        float f = pairs[code & 63]
                * pairs[64  + ((code >> 6)  & 63)]
                * pairs[128 + ((code >> 12) & 63)]
                * pairs[192 + ((code >> 18) & 63)];
        if (f > vals[7]) {
            float nv = f; int ni = r;
            #pragma unroll
            for (int k = 0; k < 8; ++k) {
                bool take = nv > vals[k];
                float cv = vals[k]; int ci = idxs[k];
                vals[k] = take ? nv : cv;
                idxs[k] = take ? ni : ci;
                nv = take ? cv : nv;
                ni = take ? ci : ni;
            }
        }
    }

    #pragma unroll
    for (int k = 0; k < 8; ++k) { svals[tid][k] = vals[k]; sidx[tid][k] = idxs[k]; }

    for (int off = 128; off >= 1; off >>= 1) {
        __syncthreads();
        if (tid < off) {
            float ov[8]; int oi[8];
            int pa = 0, pb = 0;
            #pragma unroll
            for (int k = 0; k < 8; ++k) {
                float va = svals[tid][pa];        int ia = sidx[tid][pa];
                float vb = svals[tid + off][pb];  int ib = sidx[tid + off][pb];
                bool ta = (va > vb) || ((va == vb) && (ia < ib));
                ov[k] = ta ? va : vb;
                oi[k] = ta ? ia : ib;
                pa += ta ? 1 : 0;
                pb += ta ? 0 : 1;
            }
            #pragma unroll
            for (int k = 0; k < 8; ++k) { svals[tid][k] = ov[k]; sidx[tid][k] = oi[k]; }
        }
    }
    __syncthreads();

    if (tid == 0) {
        float num = 0.0f, den = 0.0f;
        #pragma unroll
        for (int k = 0; k < 8; ++k) {
            float v = svals[0][k];
            int   c = consequents[sidx[0][k]];
            num += v * s1s[c];
            den += v * s0s[c];
        }
        out[b] = num / (den + EPSF);
    }
}

extern "C" void kernel_launch(void* const* d_in, const int* in_sizes, int n_in,
                              void* d_out, int out_size, void* d_ws, size_t ws_size,
                              hipStream_t stream) {
    const float* x      = (const float*)d_in[0];
    const int*   ant    = (const int*)d_in[1];
    const int*   cons   = (const int*)d_in[2];
    const float* in_c   = (const float*)d_in[3];
    const float* in_w   = (const float*)d_in[4];
    const float* out_c  = (const float*)d_in[5];
    const float* out_w  = (const float*)d_in[6];
    float*       out    = (float*)d_out;

    const int B = in_sizes[0] / DD;
    const int R = in_sizes[1] / DD;

    const bool shape_ok = (R == THREADS * 4 * ITERS) && (B % 2 == 0);
    const size_t need = (size_t)R * 4;    // packed words only

    if (shape_ok && d_ws && ws_size >= need) {
        unsigned* g_off = (unsigned*)d_ws;
        pack_kernel<<<(R + 255) / 256, 256, 0, stream>>>(ant, g_off, R);
        anfis2<<<B / 2, THREADS, 0, stream>>>(x, g_off, cons,
                                              in_c, in_w, out_c, out_w, out);
    } else {
        anfis_kernel<<<B, 256, 0, stream>>>(x, ant, cons, in_c, in_w,
                                            out_c, out_w, out, R);
    }
}

// Round 10
// 56.908 us; speedup vs baseline: 1.3190x; 1.0846x over previous
//
#include <hip/hip_runtime.h>
#include <math.h>

#define DD 8
#define MM 7
#define MOO 9
#define NPTS 100
#define EPSF 1e-5f

#define THREADS 1024
#define ITERS 8           // uint4 loads per thread; THREADS*4*ITERS == 32768
#define CAP 256           // candidate buffer capacity per row
// Truncated-bf16 one-sided error bounds: f~ >= 0.992203*f, m^ >= 0.988326*f.
// Thread filter uses 0.9879 < 0.988326 (safe); rule filter uses exact f >= T.
#define THR_SLACK 0.9879f

// ---------------- pack: antecedents -> packed byte-offset word --------------
// lo 16 bits: byte offset into 8B-entry quad table 0 = (code & 4095) * 8
// hi 16 bits: byte offset into 8B-entry quad table 1 = (code >> 12) * 8 + 32768
// Entry index: lo_idx = (w&0xFFFF)>>3, hi_idx = w>>19 (includes +4096 base).
__global__ __launch_bounds__(256) void pack_kernel(const int* __restrict__ ant,
                                                   unsigned* __restrict__ g_off,
                                                   int R) {
    int r = blockIdx.x * 256 + threadIdx.x;
    if (r < R) {
        const int4* a = reinterpret_cast<const int4*>(ant) + (size_t)r * 2;
        int4 lo = a[0], hi = a[1];
        int v[8] = {lo.x, lo.y, lo.z, lo.w, hi.x, hi.y, hi.z, hi.w};
        unsigned code = 0u;
        #pragma unroll
        for (int i = 0; i < 8; ++i) {
            int c = v[i];
            c = (c < 0) ? 7 : (c > MM - 1 ? MM - 1 : c);   // -1 -> wildcard slot 7
            code |= (unsigned)c << (3 * i);
        }
        g_off[r] = ((code & 4095u) << 3) | ((((code >> 12) << 3) + 32768u) << 16);
    }
}

// ---------------- main kernel: 1024 threads per FOUR batch rows -------------
// Quad tables hold 4 rows as truncated bf16 packed in uint2 (8 B): one
// ds_read_b64 serves 4 rows. Grid = B/4 = 512 -> ALL blocks resident
// (2/CU, 32 waves), single generation. Exactness: approx values are only used
// to build a provably-safe threshold; candidates are recomputed in exact f32
// (same association as R9) and selected with exact (val desc, idx asc).
__global__ __launch_bounds__(THREADS, 8) void anfis4(
    const float* __restrict__ x,
    const unsigned* __restrict__ stream_off,   // packed words, original order
    const int* __restrict__ consequents,
    const float* __restrict__ in_centers,   // [D][M]
    const float* __restrict__ in_widths,    // [D][M]
    const float* __restrict__ out_centers,  // [MO]
    const float* __restrict__ out_widths,   // [MO]
    float* __restrict__ out)
{
    __shared__ uint2   quads[8192];      // 64 KB: 2 tables x 4096, bf16x4 rows
    __shared__ float   mu[4][64];        // [row][d*8+c], c==7 -> 1.0
    __shared__ float   pairs[4][256];    // 4 KB exact f32 pair products
    __shared__ float   s0s[MOO], s1s[MOO];
    __shared__ uint2   scratch8[1024];   // 8 KB: smaxpk (ph3-4) THEN cval/cidx (ph5-6)
    __shared__ float   sT[4];            // per-row threshold T (exact domain)
    __shared__ int     scnt[4];
    __shared__ float   wv[4][8];
    __shared__ int     wc[4][8];

    const int tid = threadIdx.x;
    const int b0  = blockIdx.x * 4;

    float* cvals = (float*)scratch8;            // [4][256]
    int*   cidx  = (int*)scratch8 + 1024;       // [4][256]

    // --- phase 0: membership tables (4 rows) + defuzz constants ---
    if (tid < 256) {
        int row = tid >> 6, d = (tid >> 3) & 7, c = tid & 7;
        float v = 1.0f;
        if (c < MM) {
            float z = (x[(b0 + row) * DD + d] - in_centers[d * MM + c]) / in_widths[d * MM + c];
            v = expf(-0.5f * z * z);
            v = fminf(v, 1.0f);
            v = fmaxf(v, EPSF);
        }
        mu[row][(d << 3) + c] = v;
    } else if (tid < 256 + MOO) {
        int mo = tid - 256;
        float oc = out_centers[mo], ow = out_widths[mo];
        float s0 = 0.0f, s1 = 0.0f;
        for (int p = 0; p < NPTS; ++p) {
            float u = (float)p * (1.0f / 99.0f);
            float z = (u - oc) / ow;
            float e = expf(-0.5f * z * z);
            s0 += e;
            s1 += u * e;
        }
        s0s[mo] = s0;
        s1s[mo] = s1;
    }
    if (tid >= 512 && tid < 516) scnt[tid - 512] = 0;
    __syncthreads();

    // --- phase 1: exact pair products, 4 rows (1024 entries, one each) ---
    {
        int row = tid >> 8, e = tid & 255;
        int p = e >> 6, q = e & 63;
        pairs[row][e] = mu[row][(2 * p) * 8 + (q & 7)] * mu[row][(2 * p + 1) * 8 + (q >> 3)];
    }
    __syncthreads();

    // --- phase 2: quad tables, truncated bf16 x 4 rows per 8B entry ---
    #pragma unroll
    for (int i = 0; i < 8; ++i) {
        int k = tid + i * THREADS;
        int t = k & 4095, h = k >> 12;       // h in {0,1}
        int ia = h * 128 + (t & 63), ib = h * 128 + 64 + ((t >> 6) & 63);
        float p0 = pairs[0][ia] * pairs[0][ib];
        float p1 = pairs[1][ia] * pairs[1][ib];
        float p2 = pairs[2][ia] * pairs[2][ib];
        float p3 = pairs[3][ia] * pairs[3][ib];
        unsigned lo01 = (__float_as_uint(p1) & 0xFFFF0000u) | (__float_as_uint(p0) >> 16);
        unsigned hi23 = (__float_as_uint(p3) & 0xFFFF0000u) | (__float_as_uint(p2) >> 16);
        quads[k] = make_uint2(lo01, hi23);
    }
    __syncthreads();

    // --- phase 3: scan all rules, 4 rows per ds_read_b64 pair, track maxes ---
    const uint4* pk4 = reinterpret_cast<const uint4*>(stream_off);
    float m0 = -1.0f, m1 = -1.0f, m2 = -1.0f, m3 = -1.0f;
    {
        uint4 k0 = pk4[tid];
        uint4 k1 = pk4[1 * THREADS + tid];
        uint4 k2 = pk4[2 * THREADS + tid];
        uint4 k3 = pk4[3 * THREADS + tid];
        uint4 k4 = pk4[4 * THREADS + tid];
        uint4 k5 = pk4[5 * THREADS + tid];
        uint4 k6 = pk4[6 * THREADS + tid];
        uint4 k7 = pk4[7 * THREADS + tid];

        #define RULE(W)                                                          \
        {                                                                        \
            unsigned w_ = (W);                                                   \
            uint2 eA_ = quads[(w_ & 0xFFFFu) >> 3];                              \
            uint2 eB_ = quads[w_ >> 19];                                         \
            float a0_ = __uint_as_float(eA_.x << 16);                            \
            float a1_ = __uint_as_float(eA_.x & 0xFFFF0000u);                    \
            float a2_ = __uint_as_float(eA_.y << 16);                            \
            float a3_ = __uint_as_float(eA_.y & 0xFFFF0000u);                    \
            float b0_ = __uint_as_float(eB_.x << 16);                            \
            float b1_ = __uint_as_float(eB_.x & 0xFFFF0000u);                    \
            float b2_ = __uint_as_float(eB_.y << 16);                            \
            float b3_ = __uint_as_float(eB_.y & 0xFFFF0000u);                    \
            m0 = fmaxf(m0, a0_ * b0_);                                           \
            m1 = fmaxf(m1, a1_ * b1_);                                           \
            m2 = fmaxf(m2, a2_ * b2_);                                           \
            m3 = fmaxf(m3, a3_ * b3_);                                           \
        }
        #define PROC4(KK) RULE((KK).x) RULE((KK).y) RULE((KK).z) RULE((KK).w)
        PROC4(k0) PROC4(k1) PROC4(k2) PROC4(k3)
        PROC4(k4) PROC4(k5) PROC4(k6) PROC4(k7)
        #undef PROC4
        #undef RULE
    }
    // pack thread maxes (truncate to bf16, one-sided) into aliased buffer
    {
        unsigned pkx = (__float_as_uint(m1) & 0xFFFF0000u) | (__float_as_uint(m0) >> 16);
        unsigned pky = (__float_as_uint(m3) & 0xFFFF0000u) | (__float_as_uint(m2) >> 16);
        scratch8[tid] = make_uint2(pkx, pky);
    }
    __syncthreads();

    // --- phase 4: wave w extracts 8th-largest packed thread-max of row w ---
    if (tid < 256) {
        int w = tid >> 6, lane = tid & 63;
        float m[16];
        #pragma unroll
        for (int k = 0; k < 16; ++k) {
            uint2 e = scratch8[lane + 64 * k];
            unsigned sel = (w & 2) ? e.y : e.x;
            unsigned bits = (w & 1) ? (sel & 0xFFFF0000u) : (sel << 16);
            m[k] = __uint_as_float(bits);
        }
        float thr = -1.0f;
        #pragma unroll
        for (int round = 0; round < 8; ++round) {
            float lm = m[0];
            #pragma unroll
            for (int k = 1; k < 16; ++k) lm = fmaxf(lm, m[k]);
            float wm = lm;
            #pragma unroll
            for (int off = 32; off >= 1; off >>= 1)
                wm = fmaxf(wm, __shfl_xor(wm, off, 64));
            unsigned long long bal = __ballot(lm == wm);
            int first = (int)__ffsll(bal) - 1;
            if (lane == first) {                // remove exactly one instance
                bool done = false;
                #pragma unroll
                for (int k = 0; k < 16; ++k) {
                    bool rm = (!done) && (m[k] == wm);
                    m[k] = rm ? -2.0f : m[k];
                    done = done || rm;
                }
            }
            thr = wm;
        }
        if (lane == 0) sT[w] = thr;
    }
    __syncthreads();   // also: scratch8 reads done -> safe to reuse as cval/cidx

    // --- phase 5: qualifying threads recompute EXACT f from pairs, push ---
    {
        float mym[4] = {m0, m1, m2, m3};
        #pragma unroll
        for (int row = 0; row < 4; ++row) {
            float T = sT[row];
            if (mym[row] >= THR_SLACK * T) {       // ~30-80 threads per row
                const float* P = pairs[row];
                for (int j = 0; j < ITERS; ++j) {
                    uint4 cd = pk4[j * THREADS + tid];
                    unsigned cods[4] = {cd.x, cd.y, cd.z, cd.w};
                    #pragma unroll
                    for (int s = 0; s < 4; ++s) {
                        unsigned w = cods[s];
                        unsigned lo12 = (w & 0xFFFFu) >> 3;
                        unsigned hi12 = (w >> 19) - 4096u;
                        float f = (P[lo12 & 63u] * P[64 + (lo12 >> 6)])
                                * (P[128 + (hi12 & 63u)] * P[192 + (hi12 >> 6)]);
                        if (f >= T) {
                            int flat = (j * THREADS + tid) * 4 + s;
                            int pos = atomicAdd(&scnt[row], 1);
                            if (pos < CAP) {
                                cvals[row * CAP + pos] = f;
                                cidx[row * CAP + pos]  = flat;
                            }
                        }
                    }
                }
            }
        }
    }
    __syncthreads();

    // --- phase 6: exact rank selection per row (val desc, orig idx asc) ---
    if (tid < 256) {
        int row = tid >> 6, lane = tid & 63;
        int n = scnt[row] < CAP ? scnt[row] : CAP;
        for (int c = lane; c < n; c += 64) {
            float v  = cvals[row * CAP + c];
            int   id = cidx[row * CAP + c];
            int rk = 0;
            for (int mI = 0; mI < n; ++mI) {
                float vm = cvals[row * CAP + mI];
                int   im = cidx[row * CAP + mI];
                rk += ((vm > v) || (vm == v && im < id)) ? 1 : 0;
            }
            if (rk < 8) {
                wv[row][rk] = v;
                wc[row][rk] = consequents[id];
            }
        }
    }
    __syncthreads();

    // --- phase 7: defuzzify (one thread per row) ---
    if (tid < 4) {
        int row = tid;
        float num = 0.0f, den = 0.0f;
        #pragma unroll
        for (int k = 0; k < 8; ++k) {
            num += wv[row][k] * s1s[wc[row][k]];
            den += wv[row][k] * s0s[wc[row][k]];
        }
        out[b0 + row] = num / (den + EPSF);
    }
}

// ---------------- generic fallback (round-1 kernel, inline pack) ------------
__global__ __launch_bounds__(256) void anfis_kernel(
    const float* __restrict__ x,
    const int* __restrict__ ant,
    const int* __restrict__ consequents,
    const float* __restrict__ in_centers,
    const float* __restrict__ in_widths,
    const float* __restrict__ out_centers,
    const float* __restrict__ out_widths,
    float* __restrict__ out,
    int R)
{
    __shared__ float mu[64];
    __shared__ float pairs[256];
    __shared__ float s0s[MOO], s1s[MOO];
    __shared__ float svals[256][9];
    __shared__ int   sidx[256][9];

    const int tid = threadIdx.x;
    const int b   = blockIdx.x;

    if (tid < 64) {
        int d = tid >> 3, c = tid & 7;
        float v = 1.0f;
        if (c < MM) {
            float z = (x[b * DD + d] - in_centers[d * MM + c]) / in_widths[d * MM + c];
            v = expf(-0.5f * z * z);
            v = fminf(v, 1.0f);
            v = fmaxf(v, EPSF);
        }
        mu[tid] = v;
    } else if (tid < 64 + MOO) {
        int mo = tid - 64;
        float oc = out_centers[mo], ow = out_widths[mo];
        float s0 = 0.0f, s1 = 0.0f;
        for (int p = 0; p < NPTS; ++p) {
            float u = (float)p * (1.0f / 99.0f);
            float z = (u - oc) / ow;
            float e = expf(-0.5f * z * z);
            s0 += e;
            s1 += u * e;
        }
        s0s[mo] = s0;
        s1s[mo] = s1;
    }
    __syncthreads();

    {
        int p = tid >> 6, q = tid & 63;
        pairs[tid] = mu[(2 * p) * 8 + (q & 7)] * mu[(2 * p + 1) * 8 + (q >> 3)];
    }
    __syncthreads();

    float vals[8];
    int   idxs[8];
    #pragma unroll
    for (int k = 0; k < 8; ++k) { vals[k] = -1.0f; idxs[k] = 0x7fffffff; }

    for (int r = tid; r < R; r += 256) {
        const int4* a = reinterpret_cast<const int4*>(ant) + (size_t)r * 2;
        int4 lo = a[0], hi = a[1];
        int v[8] = {lo.x, lo.y, lo.z, lo.w, hi.x, hi.y, hi.z, hi.w};
        unsigned code = 0u;
        #pragma unroll
        for (int i = 0; i < 8; ++i) {
            int c = v[i];
            c = (c < 0) ? 7 : (c > MM - 1 ? MM - 1 : c);
            code |= (unsigned)c << (3 * i);
        }
        float f = pairs[code & 63]
                * pairs[64  + ((code >> 6)  & 63)]
                * pairs[128 + ((code >> 12) & 63)]
                * pairs[192 + ((code >> 18) & 63)];
        if (f > vals[7]) {
            float nv = f; int ni = r;
            #pragma unroll
            for (int k = 0; k < 8; ++k) {
                bool take = nv > vals[k];
                float cv = vals[k]; int ci = idxs[k];
                vals[k] = take ? nv : cv;
                idxs[k] = take ? ni : ci;
                nv = take ? cv : nv;
                ni = take ? ci : ni;
            }
        }
    }

    #pragma unroll
    for (int k = 0; k < 8; ++k) { svals[tid][k] = vals[k]; sidx[tid][k] = idxs[k]; }

    for (int off = 128; off >= 1; off >>= 1) {
        __syncthreads();
        if (tid < off) {
            float ov[8]; int oi[8];
            int pa = 0, pb = 0;
            #pragma unroll
            for (int k = 0; k < 8; ++k) {
                float va = svals[tid][pa];        int ia = sidx[tid][pa];
                float vb = svals[tid + off][pb];  int ib = sidx[tid + off][pb];
                bool ta = (va > vb) || ((va == vb) && (ia < ib));
                ov[k] = ta ? va : vb;
                oi[k] = ta ? ia : ib;
                pa += ta ? 1 : 0;
                pb += ta ? 0 : 1;
            }
            #pragma unroll
            for (int k = 0; k < 8; ++k) { svals[tid][k] = ov[k]; sidx[tid][k] = oi[k]; }
        }
    }
    __syncthreads();

    if (tid == 0) {
        float num = 0.0f, den = 0.0f;
        #pragma unroll
        for (int k = 0; k < 8; ++k) {
            float v = svals[0][k];
            int   c = consequents[sidx[0][k]];
            num += v * s1s[c];
            den += v * s0s[c];
        }
        out[b] = num / (den + EPSF);
    }
}

extern "C" void kernel_launch(void* const* d_in, const int* in_sizes, int n_in,
                              void* d_out, int out_size, void* d_ws, size_t ws_size,
                              hipStream_t stream) {
    const float* x      = (const float*)d_in[0];
    const int*   ant    = (const int*)d_in[1];
    const int*   cons   = (const int*)d_in[2];
    const float* in_c   = (const float*)d_in[3];
    const float* in_w   = (const float*)d_in[4];
    const float* out_c  = (const float*)d_in[5];
    const float* out_w  = (const float*)d_in[6];
    float*       out    = (float*)d_out;

    const int B = in_sizes[0] / DD;
    const int R = in_sizes[1] / DD;

    const bool shape_ok = (R == THREADS * 4 * ITERS) && (B % 4 == 0);
    const size_t need = (size_t)R * 4;    // packed words only

    if (shape_ok && d_ws && ws_size >= need) {
        unsigned* g_off = (unsigned*)d_ws;
        pack_kernel<<<(R + 255) / 256, 256, 0, stream>>>(ant, g_off, R);
        anfis4<<<B / 4, THREADS, 0, stream>>>(x, g_off, cons,
                                              in_c, in_w, out_c, out_w, out);
    } else {
        anfis_kernel<<<B, 256, 0, stream>>>(x, ant, cons, in_c, in_w,
                                            out_c, out_w, out, R);
    }
}